// Round 6
// baseline (280.767 us; speedup 1.0000x reference)
//
#include <hip/hip_runtime.h>

// ResLSTM: B=4096, T=512, H=32.  One wave64 = TWO batch elements.
//   half = lane>>5 selects the batch, j = lane&31 is the hidden unit;
//   lane (half,j) owns all four gate rows of unit j (i,f,g,o).
//
// History: R4 LDS h-broadcast 407->330. R5 waves_per_eu 330->316.
// R7 pins 341. R8/R9/R10 (readlane/SGPR/DPP broadcasts) all regressed ->
// LDS broadcast is the cheapest. R11 (2 batches/wave, gates lane-local):
// 341->297. R12 (v_dot2_f32_f16 MAC, prescaled f16 weights, f16 h in LDS):
// 297->248.5, absmax 9.8e-4 (passes -> ~1e-3 budget OK).
// R13 POST-MORTEM of R12: wall 1164 cy/SIMD-step, VALUBusy 80% -> 466 cy
// of issue per wave-step, but ideal-codegen hand count is only ~230 cy.
// Pressure is fine (88/256 VGPRs) -> suspect: PINALL executed PER STEP
// (4x per t4 body). Each PINALL is an asm def of 72 operands -> 288 fresh
// vregs per body the allocator must coalesce across 4 pin sites + the
// loop back-edge; failures emit v_mov churn (~100 movs/step would exactly
// explain the 2x). R13: SINGLE-VARIABLE TEST -- PINALL moved to once per
// tc iteration (32 steps). Residency still guaranteed: weights are asm
// outputs (cannot be rematerialized from memory, R6 lesson) and there is
// no spill pressure. Math untouched -> absmax must stay 0.0009765625.
// Predict: 248 -> 140-200 us if churn theory right; neutral if wrong
// (then: disasm-guided round or pk_fma_f16/MFMA restructure).

static constexpr int T_LEN = 512;
static constexpr int H = 32;

typedef _Float16 h2 __attribute__((ext_vector_type(2)));

// float bit-pattern -> packed f16 pair
__device__ __forceinline__ h2 bch(float f) { return __builtin_bit_cast(h2, f); }

// D = dot2(a, b) + c  : 2 f16 MACs, fp32 accumulate (v_dot2_f32_f16)
__device__ __forceinline__ float fd2(float wbits, h2 p, float acc) {
#if __has_builtin(__builtin_amdgcn_fdot2)
    return __builtin_amdgcn_fdot2(__builtin_bit_cast(h2, wbits), p, acc, false);
#else
    float d = acc;
    asm("v_dot2_f32_f16 %0, %1, %2, %0"
        : "+v"(d) : "v"(__builtin_bit_cast(h2, wbits)), "v"(p));
    return d;
#endif
}

// pack two fp32 (prescaled) weights into one f16-pair bit pattern
__device__ __forceinline__ float packw(float w0, float w1) {
    h2 p;
    p[0] = (_Float16)w0;
    p[1] = (_Float16)w1;
    return __builtin_bit_cast(float, p);
}

__global__ void
__attribute__((amdgpu_flat_work_group_size(256, 256), amdgpu_waves_per_eu(2, 2)))
reslstm_kernel(const float* __restrict__ x,
               const float* __restrict__ W_ih,
               const float* __restrict__ W_hh,
               const float* __restrict__ b_ih,
               const float* __restrict__ b_hh,
               const float* __restrict__ W_fc,
               const float* __restrict__ b_fc,
               float* __restrict__ out, int B)
{
    // h as f16: [wave][half][40] (pad 80 B -> halves' same-address broadcast
    // groups sit 20 banks apart; all four b128 reads conflict-free).
    __shared__ _Float16 hbufh[4][2][40];
    __shared__ float    xbuf[4][72];     // [wave][half*36 + j]: 32-step x chunk

    const int lane = threadIdx.x & 63;
    const int wv   = threadIdx.x >> 6;
    const int j    = lane & 31;          // hidden unit
    const int half = lane >> 5;          // which batch of the pair

    const int b0 = (blockIdx.x << 3) + (wv << 1);
    if (b0 >= B) return;                 // wave-uniform guard
    const int bb   = b0 + half;
    const int bsrc = (bb < B) ? bb : b0; // clamp loads; store is guarded

    constexpr float NL2E  = -1.4426950408889634f;   // -log2(e)
    constexpr float N2L2E = 2.0f * NL2E;

    // W_hh rows for unit j, all four gates, PRESCALED (i,f,o: *NL2E;
    // g: *2NL2E) and packed to f16 pairs -> 64 VGPRs total.
    float wi2[16], wf2[16], wg2[16], wo2[16];
    {
        const float* ri = W_hh + (j     ) * H;
        const float* rf = W_hh + (j + 32) * H;
        const float* rg = W_hh + (j + 64) * H;
        const float* ro = W_hh + (j + 96) * H;
        #pragma unroll
        for (int k = 0; k < 16; ++k) {
            wi2[k] = packw(ri[2*k] * NL2E,  ri[2*k+1] * NL2E);
            wf2[k] = packw(rf[2*k] * NL2E,  rf[2*k+1] * NL2E);
            wg2[k] = packw(rg[2*k] * N2L2E, rg[2*k+1] * N2L2E);
            wo2[k] = packw(ro[2*k] * NL2E,  ro[2*k+1] * NL2E);
        }
    }

    // x-projection weights & biases: fp32, prescaled.
    float wihi = W_ih[j]      * NL2E;
    float wihf = W_ih[j + 32] * NL2E;
    float wihg = W_ih[j + 64] * N2L2E;
    float wiho = W_ih[j + 96] * NL2E;
    float bi  = (b_ih[j]      + b_hh[j])      * NL2E;
    float bfv = (b_ih[j + 32] + b_hh[j + 32]) * NL2E;
    float bgv = (b_ih[j + 64] + b_hh[j + 64]) * N2L2E;
    float bov = (b_ih[j + 96] + b_hh[j + 96]) * NL2E;

    float h = 0.0f, c = 0.0f;
    hbufh[wv][half][j] = (_Float16)0.0f;      // h0 = 0 (wave-synchronous)

    const float* xrow = x + (size_t)bsrc * T_LEN;
    const float4* hb = reinterpret_cast<const float4*>(&hbufh[wv][half][0]);
    const float4* xb = reinterpret_cast<const float4*>(&xbuf[wv][half * 36]);

// Volatile pins (R6/R7 lesson): outputs feed the next tc iteration;
// reloading pinned values from memory is illegal -> weights stay
// VGPR-resident. R13: executed once per 32 steps (was per step) to kill
// allocator mov-churn from 4 pin sites per loop body.
#define PIN16(P)                                                              \
    asm volatile("" : "+v"((P)[0]),  "+v"((P)[1]),  "+v"((P)[2]),  "+v"((P)[3]), \
                      "+v"((P)[4]),  "+v"((P)[5]),  "+v"((P)[6]),  "+v"((P)[7]), \
                      "+v"((P)[8]),  "+v"((P)[9]),  "+v"((P)[10]), "+v"((P)[11]),\
                      "+v"((P)[12]), "+v"((P)[13]), "+v"((P)[14]), "+v"((P)[15]))
#define PINALL()                                                              \
    PIN16(wi2); PIN16(wf2); PIN16(wg2); PIN16(wo2);                           \
    asm volatile("" : "+v"(wihi), "+v"(wihf), "+v"(wihg), "+v"(wiho),         \
                      "+v"(bi), "+v"(bfv), "+v"(bgv), "+v"(bov))

// 16 dot2 against one broadcast float4 (= 8 f16 = 4 h-pairs).
// Pairs M+0,M+2 -> chain1; M+1,M+3 -> chain2.
#define MACQ(HQ, M)                                                           \
    {   const h2 p0 = bch(HQ.x), p1 = bch(HQ.y),                              \
                 p2 = bch(HQ.z), p3 = bch(HQ.w);                              \
        a1i = fd2(wi2[M+0], p0, a1i); a1f = fd2(wf2[M+0], p0, a1f);           \
        a1g = fd2(wg2[M+0], p0, a1g); a1o = fd2(wo2[M+0], p0, a1o);           \
        a2i = fd2(wi2[M+1], p1, a2i); a2f = fd2(wf2[M+1], p1, a2f);           \
        a2g = fd2(wg2[M+1], p1, a2g); a2o = fd2(wo2[M+1], p1, a2o);           \
        a1i = fd2(wi2[M+2], p2, a1i); a1f = fd2(wf2[M+2], p2, a1f);           \
        a1g = fd2(wg2[M+2], p2, a1g); a1o = fd2(wo2[M+2], p2, a1o);           \
        a2i = fd2(wi2[M+3], p3, a2i); a2f = fd2(wf2[M+3], p3, a2f);           \
        a2g = fd2(wg2[M+3], p3, a2g); a2o = fd2(wo2[M+3], p3, a2o);           \
    }

#define STEP(XT) do {                                                         \
    float a1i = __builtin_fmaf(XT, wihi, bi);                                 \
    float a1f = __builtin_fmaf(XT, wihf, bfv);                                \
    float a1g = __builtin_fmaf(XT, wihg, bgv);                                \
    float a1o = __builtin_fmaf(XT, wiho, bov);                                \
    float a2i = 0.0f, a2f = 0.0f, a2g = 0.0f, a2o = 0.0f;                     \
    {   /* h(t-1) broadcast: 4x same-address b128 per half (32 f16) */        \
        const float4 h0 = hb[0], h1 = hb[1], h2q = hb[2], h3 = hb[3];         \
        MACQ(h0, 0) MACQ(h1, 4) MACQ(h2q, 8) MACQ(h3, 12)                     \
    }                                                                         \
    const float ai = a1i + a2i, af_ = a1f + a2f;                              \
    const float ag = a1g + a2g, ao  = a1o + a2o;                              \
    /* accumulators are already -log2(e)-scaled: gate = rcp(1+exp2(a)) */     \
    const float gi = __builtin_amdgcn_rcpf(1.0f + __builtin_amdgcn_exp2f(ai));  \
    const float gf = __builtin_amdgcn_rcpf(1.0f + __builtin_amdgcn_exp2f(af_)); \
    const float go = __builtin_amdgcn_rcpf(1.0f + __builtin_amdgcn_exp2f(ao));  \
    const float gg = __builtin_fmaf(2.0f,                                     \
        __builtin_amdgcn_rcpf(1.0f + __builtin_amdgcn_exp2f(ag)), -1.0f);     \
    c = __builtin_fmaf(gf, c, gi * gg);                                       \
    const float th = __builtin_fmaf(2.0f,                                     \
        __builtin_amdgcn_rcpf(1.0f + __builtin_amdgcn_exp2f(c * N2L2E)), -1.0f); \
    h = go * th;                                                              \
    hbufh[wv][half][j] = (_Float16)h;        /* publish for next step */      \
} while (0)

    float xcur = xrow[j];                     // chunk 0 of this half's batch
    for (int tc = 0; tc < T_LEN / 32; ++tc) {
        PINALL();                             // R13: once per 32 steps
        xbuf[wv][half * 36 + j] = xcur;       // stage 32 steps of x
        float xnext = 0.0f;
        if (tc + 1 < T_LEN / 32) xnext = xrow[(tc + 1) * 32 + j];  // prefetch
        for (int t4 = 0; t4 < 8; ++t4) {
            const float4 xq = xb[t4];         // 4 steps of x, broadcast/half
            STEP(xq.x); STEP(xq.y); STEP(xq.z); STEP(xq.w);
        }
        xcur = xnext;
    }
#undef STEP
#undef MACQ
#undef PINALL
#undef PIN16

    // out[bb] = sum_j h[j]*W_fc[j] + b_fc  (butterfly within each half)
    float val = h * W_fc[j];
    #pragma unroll
    for (int off = 16; off >= 1; off >>= 1)
        val += __shfl_xor(val, off);
    if (j == 0 && bb < B) out[bb] = val + b_fc[0];
}

extern "C" void kernel_launch(void* const* d_in, const int* in_sizes, int n_in,
                              void* d_out, int out_size, void* d_ws, size_t ws_size,
                              hipStream_t stream) {
    const float* x    = (const float*)d_in[0];
    const float* W_ih = (const float*)d_in[1];
    const float* W_hh = (const float*)d_in[2];
    const float* b_ih = (const float*)d_in[3];
    const float* b_hh = (const float*)d_in[4];
    const float* W_fc = (const float*)d_in[5];
    const float* b_fc = (const float*)d_in[6];
    float* out = (float*)d_out;
    const int B = in_sizes[0] / T_LEN;        // 4096
    dim3 block(256);                          // 4 waves = 8 batch elements
    dim3 grid((B + 7) / 8);                   // 512 blocks -> 2 waves/SIMD
    reslstm_kernel<<<grid, block, 0, stream>>>(x, W_ih, W_hh, b_ih, b_hh,
                                               W_fc, b_fc, out, B);
}

// Round 7
// 275.276 us; speedup vs baseline: 1.0199x; 1.0199x over previous
//
#include <hip/hip_runtime.h>

// ResLSTM: B=4096, T=512, H=32.  One wave64 = TWO batch elements.
//   half = lane>>5 selects the batch, j = lane&31 is the hidden unit;
//   lane (half,j) owns all four gate rows of unit j (i,f,g,o).
//
// History: R4 LDS h-broadcast 407->330. R5 waves_per_eu 330->316.
// R7 pins 341 (LDS-pipe floor at 4 waves/SIMD). R8/R9/R10 readlane/SGPR/DPP
// broadcasts all regressed -> LDS broadcast is cheapest. R11 2-batch/wave:
// 341->297. R12 v_dot2_f32_f16 MAC: 297->248.5, absmax 9.8e-4 (passes).
// R13 pin-hoist: NEUTRAL -> pin churn theory dead.
// R14 POST-MORTEM MODEL: busy/wave-step 466 cy vs 168 cy of non-trans
// issue. R7 (288 busy, 6 trans) and R12 (466 busy, 10 trans) jointly fit
// wave64 v_exp/v_rcp occupying ~21-30 cy of VALU issue each (NOT ~8).
// => the 10 transcendentals are ~60% of VALU busy; MAC dot2 is only 128 cy.
// R14: ALGEBRAIC TRANS REDUCTION 10 -> 7 (5 exp2 + 2 rcp):
//   c' = gf*c + gi*gg = [c*Di*Dg + (1-Eg)*Df] / (Df*Di*Dg)   ... 1 rcp
//   h  = go*tanh(c)   = (1-Ec) / (Do*Dc)                     ... 1 rcp
// (E*=exp2(scaled preact), D*=1+E*; |scaled|<~8 -> no overflow.)
// Cost: -3 rcp, +3 cheap VALU. Predict 249 -> 220-235 us if the trans-issue
// model holds; neutral falsifies it (then: dep-chain/LDS latency round).

static constexpr int T_LEN = 512;
static constexpr int H = 32;

typedef _Float16 h2 __attribute__((ext_vector_type(2)));

// float bit-pattern -> packed f16 pair
__device__ __forceinline__ h2 bch(float f) { return __builtin_bit_cast(h2, f); }

// D = dot2(a, b) + c  : 2 f16 MACs, fp32 accumulate (v_dot2_f32_f16)
__device__ __forceinline__ float fd2(float wbits, h2 p, float acc) {
#if __has_builtin(__builtin_amdgcn_fdot2)
    return __builtin_amdgcn_fdot2(__builtin_bit_cast(h2, wbits), p, acc, false);
#else
    float d = acc;
    asm("v_dot2_f32_f16 %0, %1, %2, %0"
        : "+v"(d) : "v"(__builtin_bit_cast(h2, wbits)), "v"(p));
    return d;
#endif
}

// pack two fp32 (prescaled) weights into one f16-pair bit pattern
__device__ __forceinline__ float packw(float w0, float w1) {
    h2 p;
    p[0] = (_Float16)w0;
    p[1] = (_Float16)w1;
    return __builtin_bit_cast(float, p);
}

__global__ void
__attribute__((amdgpu_flat_work_group_size(256, 256), amdgpu_waves_per_eu(2, 2)))
reslstm_kernel(const float* __restrict__ x,
               const float* __restrict__ W_ih,
               const float* __restrict__ W_hh,
               const float* __restrict__ b_ih,
               const float* __restrict__ b_hh,
               const float* __restrict__ W_fc,
               const float* __restrict__ b_fc,
               float* __restrict__ out, int B)
{
    // h as f16: [wave][half][40] (pad 80 B -> halves' same-address broadcast
    // groups sit 20 banks apart; all four b128 reads conflict-free).
    __shared__ _Float16 hbufh[4][2][40];
    __shared__ float    xbuf[4][72];     // [wave][half*36 + j]: 32-step x chunk

    const int lane = threadIdx.x & 63;
    const int wv   = threadIdx.x >> 6;
    const int j    = lane & 31;          // hidden unit
    const int half = lane >> 5;          // which batch of the pair

    const int b0 = (blockIdx.x << 3) + (wv << 1);
    if (b0 >= B) return;                 // wave-uniform guard
    const int bb   = b0 + half;
    const int bsrc = (bb < B) ? bb : b0; // clamp loads; store is guarded

    constexpr float NL2E  = -1.4426950408889634f;   // -log2(e)
    constexpr float N2L2E = 2.0f * NL2E;

    // W_hh rows for unit j, all four gates, PRESCALED (i,f,o: *NL2E;
    // g: *2NL2E) and packed to f16 pairs -> 64 VGPRs total.
    float wi2[16], wf2[16], wg2[16], wo2[16];
    {
        const float* ri = W_hh + (j     ) * H;
        const float* rf = W_hh + (j + 32) * H;
        const float* rg = W_hh + (j + 64) * H;
        const float* ro = W_hh + (j + 96) * H;
        #pragma unroll
        for (int k = 0; k < 16; ++k) {
            wi2[k] = packw(ri[2*k] * NL2E,  ri[2*k+1] * NL2E);
            wf2[k] = packw(rf[2*k] * NL2E,  rf[2*k+1] * NL2E);
            wg2[k] = packw(rg[2*k] * N2L2E, rg[2*k+1] * N2L2E);
            wo2[k] = packw(ro[2*k] * NL2E,  ro[2*k+1] * NL2E);
        }
    }

    // x-projection weights & biases: fp32, prescaled.
    float wihi = W_ih[j]      * NL2E;
    float wihf = W_ih[j + 32] * NL2E;
    float wihg = W_ih[j + 64] * N2L2E;
    float wiho = W_ih[j + 96] * NL2E;
    float bi  = (b_ih[j]      + b_hh[j])      * NL2E;
    float bfv = (b_ih[j + 32] + b_hh[j + 32]) * NL2E;
    float bgv = (b_ih[j + 64] + b_hh[j + 64]) * N2L2E;
    float bov = (b_ih[j + 96] + b_hh[j + 96]) * NL2E;

    float h = 0.0f, c = 0.0f;
    hbufh[wv][half][j] = (_Float16)0.0f;      // h0 = 0 (wave-synchronous)

    const float* xrow = x + (size_t)bsrc * T_LEN;
    const float4* hb = reinterpret_cast<const float4*>(&hbufh[wv][half][0]);
    const float4* xb = reinterpret_cast<const float4*>(&xbuf[wv][half * 36]);

// Volatile pins (R6/R7 lesson): outputs feed the next tc iteration;
// reloading pinned values from memory is illegal -> weights stay
// VGPR-resident. Once per 32 steps (R13: per-step vs per-tc is neutral).
#define PIN16(P)                                                              \
    asm volatile("" : "+v"((P)[0]),  "+v"((P)[1]),  "+v"((P)[2]),  "+v"((P)[3]), \
                      "+v"((P)[4]),  "+v"((P)[5]),  "+v"((P)[6]),  "+v"((P)[7]), \
                      "+v"((P)[8]),  "+v"((P)[9]),  "+v"((P)[10]), "+v"((P)[11]),\
                      "+v"((P)[12]), "+v"((P)[13]), "+v"((P)[14]), "+v"((P)[15]))
#define PINALL()                                                              \
    PIN16(wi2); PIN16(wf2); PIN16(wg2); PIN16(wo2);                           \
    asm volatile("" : "+v"(wihi), "+v"(wihf), "+v"(wihg), "+v"(wiho),         \
                      "+v"(bi), "+v"(bfv), "+v"(bgv), "+v"(bov))

// 16 dot2 against one broadcast float4 (= 8 f16 = 4 h-pairs).
// Pairs M+0,M+2 -> chain1; M+1,M+3 -> chain2.
#define MACQ(HQ, M)                                                           \
    {   const h2 p0 = bch(HQ.x), p1 = bch(HQ.y),                              \
                 p2 = bch(HQ.z), p3 = bch(HQ.w);                              \
        a1i = fd2(wi2[M+0], p0, a1i); a1f = fd2(wf2[M+0], p0, a1f);           \
        a1g = fd2(wg2[M+0], p0, a1g); a1o = fd2(wo2[M+0], p0, a1o);           \
        a2i = fd2(wi2[M+1], p1, a2i); a2f = fd2(wf2[M+1], p1, a2f);           \
        a2g = fd2(wg2[M+1], p1, a2g); a2o = fd2(wo2[M+1], p1, a2o);           \
        a1i = fd2(wi2[M+2], p2, a1i); a1f = fd2(wf2[M+2], p2, a1f);           \
        a1g = fd2(wg2[M+2], p2, a1g); a1o = fd2(wo2[M+2], p2, a1o);           \
        a2i = fd2(wi2[M+3], p3, a2i); a2f = fd2(wf2[M+3], p3, a2f);           \
        a2g = fd2(wg2[M+3], p3, a2g); a2o = fd2(wo2[M+3], p3, a2o);           \
    }

// R14 gate math: E* = exp2(scaled preact), D* = 1+E*.
//   c' = [c*Di*Dg + (1-Eg)*Df] * rcp(Df*Di*Dg)        (gf*c + gi*gg)
//   h  = (1-Ec) * rcp(Do*Dc),  Ec = exp2(c*N2L2E)     (go*tanh(c))
// 5 exp2 + 2 rcp = 7 trans (was 10).
#define STEP(XT) do {                                                         \
    float a1i = __builtin_fmaf(XT, wihi, bi);                                 \
    float a1f = __builtin_fmaf(XT, wihf, bfv);                                \
    float a1g = __builtin_fmaf(XT, wihg, bgv);                                \
    float a1o = __builtin_fmaf(XT, wiho, bov);                                \
    float a2i = 0.0f, a2f = 0.0f, a2g = 0.0f, a2o = 0.0f;                     \
    {   /* h(t-1) broadcast: 4x same-address b128 per half (32 f16) */        \
        const float4 h0 = hb[0], h1 = hb[1], h2q = hb[2], h3 = hb[3];         \
        MACQ(h0, 0) MACQ(h1, 4) MACQ(h2q, 8) MACQ(h3, 12)                     \
    }                                                                         \
    const float Ei = __builtin_amdgcn_exp2f(a1i + a2i);                       \
    const float Ef = __builtin_amdgcn_exp2f(a1f + a2f);                       \
    const float Eg = __builtin_amdgcn_exp2f(a1g + a2g);                       \
    const float Eo = __builtin_amdgcn_exp2f(a1o + a2o);                       \
    const float Di = 1.0f + Ei, Df = 1.0f + Ef;                               \
    const float Dg = 1.0f + Eg, Do_ = 1.0f + Eo;                              \
    const float P  = Di * Dg;                                                 \
    const float t_ = (1.0f - Eg) * Df;                                        \
    const float u_ = __builtin_fmaf(c, P, t_);                                \
    const float Rc = __builtin_amdgcn_rcpf(Df * P);                           \
    c = u_ * Rc;                                                              \
    const float Ec = __builtin_amdgcn_exp2f(c * N2L2E);                       \
    const float Dc = 1.0f + Ec;                                               \
    const float Rh = __builtin_amdgcn_rcpf(Do_ * Dc);                         \
    h = (1.0f - Ec) * Rh;                                                     \
    hbufh[wv][half][j] = (_Float16)h;        /* publish for next step */      \
} while (0)

    float xcur = xrow[j];                     // chunk 0 of this half's batch
    for (int tc = 0; tc < T_LEN / 32; ++tc) {
        PINALL();                             // once per 32 steps
        xbuf[wv][half * 36 + j] = xcur;       // stage 32 steps of x
        float xnext = 0.0f;
        if (tc + 1 < T_LEN / 32) xnext = xrow[(tc + 1) * 32 + j];  // prefetch
        for (int t4 = 0; t4 < 8; ++t4) {
            const float4 xq = xb[t4];         // 4 steps of x, broadcast/half
            STEP(xq.x); STEP(xq.y); STEP(xq.z); STEP(xq.w);
        }
        xcur = xnext;
    }
#undef STEP
#undef MACQ
#undef PINALL
#undef PIN16

    // out[bb] = sum_j h[j]*W_fc[j] + b_fc  (butterfly within each half)
    float val = h * W_fc[j];
    #pragma unroll
    for (int off = 16; off >= 1; off >>= 1)
        val += __shfl_xor(val, off);
    if (j == 0 && bb < B) out[bb] = val + b_fc[0];
}

extern "C" void kernel_launch(void* const* d_in, const int* in_sizes, int n_in,
                              void* d_out, int out_size, void* d_ws, size_t ws_size,
                              hipStream_t stream) {
    const float* x    = (const float*)d_in[0];
    const float* W_ih = (const float*)d_in[1];
    const float* W_hh = (const float*)d_in[2];
    const float* b_ih = (const float*)d_in[3];
    const float* b_hh = (const float*)d_in[4];
    const float* W_fc = (const float*)d_in[5];
    const float* b_fc = (const float*)d_in[6];
    float* out = (float*)d_out;
    const int B = in_sizes[0] / T_LEN;        // 4096
    dim3 block(256);                          // 4 waves = 8 batch elements
    dim3 grid((B + 7) / 8);                   // 512 blocks -> 2 waves/SIMD
    reslstm_kernel<<<grid, block, 0, stream>>>(x, W_ih, W_hh, b_ih, b_hh,
                                               W_fc, b_fc, out, B);
}